// Round 2
// baseline (475.528 us; speedup 1.0000x reference)
//
#include <hip/hip_runtime.h>
#include <cstdint>
#include <cstddef>

typedef _Float16 f16;
typedef f16 f16x8 __attribute__((ext_vector_type(8)));
typedef float f32x4 __attribute__((ext_vector_type(4)));

#define B_ROWS 65536
#define NT_BRANCH 1030   // worst-case branch tiles: 1024 + 6 bins' padding
#define NT_SPEED 1024    // 65536/64

// ---------------- ws layout (all offsets 256B-aligned) ----------------
constexpr size_t OFF_EMBF16 = 0;
constexpr size_t SZ_EMBF16  = (size_t)B_ROWS * 640 * 2;        // 83,886,080
constexpr size_t OFF_SIW2T  = OFF_EMBF16 + SZ_EMBF16;
constexpr size_t SZ_SIW2T   = (size_t)128 * 256 * 2;
constexpr size_t OFF_BW1T   = OFF_SIW2T + SZ_SIW2T;
constexpr size_t SZ_BW1T    = (size_t)6 * 256 * 640 * 2;
constexpr size_t OFF_BW2T   = OFF_BW1T + SZ_BW1T;
constexpr size_t SZ_BW2T    = (size_t)6 * 256 * 256 * 2;
constexpr size_t OFF_SOW1T  = OFF_BW2T + SZ_BW2T;
constexpr size_t SZ_SOW1T   = (size_t)256 * 640 * 2;
constexpr size_t OFF_SOW2T  = OFF_SOW1T + SZ_SOW1T;
constexpr size_t SZ_SOW2T   = (size_t)256 * 256 * 2;
constexpr size_t OFF_BW3T16 = OFF_SOW2T + SZ_SOW2T;
constexpr size_t SZ_BW3T16  = (size_t)6 * 16 * 256 * 2;        // zero-padded cols 3..15
constexpr size_t OFF_SOW3T16= OFF_BW3T16 + SZ_BW3T16;
constexpr size_t SZ_SOW3T16 = (size_t)16 * 256 * 2;
constexpr size_t OFF_COUNTS = OFF_SOW3T16 + SZ_SOW3T16;
constexpr size_t OFF_CURSORS= OFF_COUNTS + 256;
constexpr size_t OFF_BINBASE= OFF_CURSORS + 256;
constexpr size_t OFF_TILECMD= OFF_BINBASE + 256;
constexpr size_t OFF_PERM   = OFF_TILECMD + 4352;
constexpr size_t WS_NEEDED  = OFF_PERM + (size_t)NT_BRANCH * 64 * 4;  // ~87.5 MB

// ---------------- prep: transpose-cast weights + W3T16 + init sort scratch ----------------
__global__ void prep_kernel(const float* __restrict__ siW2,
                            const float* __restrict__ bW1,
                            const float* __restrict__ bW2,
                            const float* __restrict__ soW1,
                            const float* __restrict__ soW2,
                            const float* __restrict__ bW3,
                            const float* __restrict__ soW3,
                            f16* __restrict__ siW2T, f16* __restrict__ bW1T,
                            f16* __restrict__ bW2T, f16* __restrict__ soW1T,
                            f16* __restrict__ soW2T,
                            f16* __restrict__ bW3T16, f16* __restrict__ soW3T16,
                            int* __restrict__ counts, int* __restrict__ cursors,
                            int* __restrict__ perm)
{
    const int bx = blockIdx.x;
    const int tx = threadIdx.x, ty = threadIdx.y;
    const int tid = ty * 32 + tx;
    if (bx >= 1601) {                       // perm init + counter zero
        const int ib = bx - 1601;
        const int idx = ib * 256 + tid;
        if (idx < NT_BRANCH * 64) perm[idx] = -1;
        if (ib == 0 && tid < 6) { counts[tid] = 0; cursors[tid] = 0; }
        return;
    }
    if (bx == 1600) {                       // W3 -> padded-16-col f16, [n][k] layout
        for (int i = tid; i < 6 * 16 * 256; i += 256) {
            const int c = i >> 12, rem = i & 4095, n = rem >> 8, k = rem & 255;
            bW3T16[i] = (n < 3) ? (f16)bW3[((size_t)c * 256 + k) * 3 + n] : (f16)0;
        }
        for (int i = tid; i < 16 * 256; i += 256) {
            const int n = i >> 8, k = i & 255;
            soW3T16[i] = (n == 0) ? (f16)soW3[k] : (f16)0;
        }
        return;
    }
    const float* in; f16* out; int R, C, lb;
    if (bx < 960)       { int m = bx / 160;        lb = bx - m * 160;       in = bW1 + (size_t)m * 640 * 256; out = bW1T + (size_t)m * 640 * 256; R = 640; C = 256; }
    else if (bx < 1344) { int m = (bx - 960) / 64; lb = (bx - 960) - m * 64; in = bW2 + (size_t)m * 256 * 256; out = bW2T + (size_t)m * 256 * 256; R = 256; C = 256; }
    else if (bx < 1504) { lb = bx - 1344; in = soW1; out = soW1T; R = 640; C = 256; }
    else if (bx < 1568) { lb = bx - 1504; in = soW2; out = soW2T; R = 256; C = 256; }
    else                { lb = bx - 1568; in = siW2; out = siW2T; R = 256; C = 128; }
    const int txt = C >> 5;
    const int c0 = (lb % txt) << 5;
    const int r0 = (lb / txt) << 5;
    __shared__ float tile[32][33];
    #pragma unroll
    for (int i = 0; i < 4; ++i)
        tile[tx][ty + 8 * i] = in[(size_t)(r0 + ty + 8 * i) * C + c0 + tx];
    __syncthreads();
    #pragma unroll
    for (int i = 0; i < 4; ++i)
        out[(size_t)(c0 + ty + 8 * i) * R + r0 + tx] = (f16)tile[ty + 8 * i][tx];
}

// ---------------- pack: embF16 = [cast(emb) | speed_in MLP], fused histogram ----------------
__global__ __launch_bounds__(256) void pack_kernel(
    const float* __restrict__ emb, const float* __restrict__ speed,
    const float* __restrict__ siW1, const float* __restrict__ sib1,
    const f16* __restrict__ siW2T, const float* __restrict__ sib2,
    const int* __restrict__ cmd,
    f16* __restrict__ embF16, int* __restrict__ counts)
{
    __shared__ f16 H[64 * 264];
    __shared__ float spd[64];
    __shared__ int h[6];
    const int tid = threadIdx.x;
    const int rb = blockIdx.x * 64;
    if (tid < 6) h[tid] = 0;
    __syncthreads();
    if (tid < 64) {
        spd[tid] = speed[rb + tid];
        atomicAdd(&h[cmd[rb + tid] - 1], 1);
    }
    __syncthreads();
    if (tid < 6 && h[tid] > 0) atomicAdd(&counts[tid], h[tid]);
    {   // hidden layer of speed_in (K=1)
        const float w1 = siW1[tid], b1v = sib1[tid];
        #pragma unroll 4
        for (int r = 0; r < 64; ++r) {
            float hv = spd[r] * w1 + b1v;
            H[r * 264 + tid] = (f16)(hv > 0.f ? hv : 0.f);
        }
    }
    // coalesced cast-copy of embedding cols 0..511 (one wave per row per pass)
    #pragma unroll
    for (int i = tid; i < 4096; i += 256) {
        const int r = i >> 6, c8 = (i & 63) << 3;
        const float* src = emb + (size_t)(rb + r) * 512 + c8;
        const float4 p0 = *(const float4*)(src);
        const float4 p1 = *(const float4*)(src + 4);
        f16x8 v;
        v[0] = (f16)p0.x; v[1] = (f16)p0.y; v[2] = (f16)p0.z; v[3] = (f16)p0.w;
        v[4] = (f16)p1.x; v[5] = (f16)p1.y; v[6] = (f16)p1.z; v[7] = (f16)p1.w;
        *(f16x8*)(embF16 + (size_t)(rb + r) * 640 + c8) = v;
    }
    __syncthreads();
    // second layer: [64,256]@[256,128] via MFMA -> cols 512..639
    const int w = tid >> 6, lane = tid & 63, lq = lane >> 4, l16 = lane & 15;
    const int nb = w * 32;
    f32x4 acc[4][2];
    #pragma unroll
    for (int mt = 0; mt < 4; ++mt)
        #pragma unroll
        for (int nt = 0; nt < 2; ++nt)
            acc[mt][nt] = (f32x4){0.f, 0.f, 0.f, 0.f};
    for (int ks = 0; ks < 8; ++ks) {
        const int koff = ks * 32 + lq * 8;
        f16x8 af[4], bf[2];
        #pragma unroll
        for (int mt = 0; mt < 4; ++mt)
            af[mt] = *(const f16x8*)(&H[(mt * 16 + l16) * 264 + koff]);
        #pragma unroll
        for (int nt = 0; nt < 2; ++nt)
            bf[nt] = *(const f16x8*)(siW2T + (size_t)(nb + nt * 16 + l16) * 256 + koff);
        #pragma unroll
        for (int mt = 0; mt < 4; ++mt)
            #pragma unroll
            for (int nt = 0; nt < 2; ++nt)
                acc[mt][nt] = __builtin_amdgcn_mfma_f32_16x16x32_f16(af[mt], bf[nt], acc[mt][nt], 0, 0, 0);
    }
    #pragma unroll
    for (int mt = 0; mt < 4; ++mt)
        #pragma unroll
        for (int nt = 0; nt < 2; ++nt) {
            const int n = nb + nt * 16 + l16;
            const float bv = sib2[n];
            #pragma unroll
            for (int r2 = 0; r2 < 4; ++r2) {
                const int m = mt * 16 + lq * 4 + r2;
                embF16[(size_t)(rb + m) * 640 + 512 + n] = (f16)(acc[mt][nt][r2] + bv);
            }
        }
}

// ---------------- plan: bin bases + tile->command map ----------------
__global__ void plan_kernel(const int* __restrict__ counts,
                            int* __restrict__ binBase, int* __restrict__ tile_cmd) {
    __shared__ int tbase[7];
    if (threadIdx.x == 0) {
        int base = 0, tb = 0;
        for (int c = 0; c < 6; ++c) {
            binBase[c] = base;
            tbase[c] = tb;
            const int nt = (counts[c] + 63) >> 6;
            tb += nt;
            base += nt << 6;
        }
        tbase[6] = tb;
    }
    __syncthreads();
    for (int t = threadIdx.x; t < NT_BRANCH; t += 256) {
        int c = -1;
        #pragma unroll
        for (int j = 0; j < 6; ++j)
            if (t >= tbase[j] && t < tbase[j + 1]) c = j;
        tile_cmd[t] = c;
    }
}

__global__ void place_kernel(const int* __restrict__ cmd,
                             const int* __restrict__ binBase,
                             int* __restrict__ cursors, int* __restrict__ perm) {
    __shared__ int lcnt[6], lbase[6];
    const int tid = threadIdx.x;
    if (tid < 6) lcnt[tid] = 0;
    __syncthreads();
    const int i = blockIdx.x * 256 + tid;
    const int c = cmd[i] - 1;
    const int myr = atomicAdd(&lcnt[c], 1);
    __syncthreads();
    if (tid < 6) lbase[tid] = atomicAdd(&cursors[tid], lcnt[tid]);
    __syncthreads();
    perm[binBase[c] + lbase[c] + myr] = i;
}

// ---------------- heads: fused 3-layer MLP, barrier-free GEMM1 K-loop ----------------
__global__ __launch_bounds__(256, 3) void heads_kernel(
    const f16* __restrict__ embF16,
    const int* __restrict__ perm, const int* __restrict__ tile_cmd,
    const f16* __restrict__ bW1T, const f16* __restrict__ bW2T,
    const f16* __restrict__ bW3T16,
    const float* __restrict__ bb1, const float* __restrict__ bb2,
    const float* __restrict__ bb3,
    const f16* __restrict__ soW1T, const f16* __restrict__ soW2T,
    const f16* __restrict__ soW3T16,
    const float* __restrict__ sob1, const float* __restrict__ sob2,
    const float* __restrict__ sob3,
    float* __restrict__ out)
{
    __shared__ f16 lds[64 * 264];      // h1 then h2, [64][264] (stride pad -> 2-way max)
    __shared__ int rowIdx[64];
    const int bx = blockIdx.x;
    const int tid = threadIdx.x;
    const bool is_speed = (bx >= NT_BRANCH);
    const f16 *W1T, *W2T, *W3T;
    const float *bias1, *bias2, *bias3;
    if (is_speed) {
        const int t = bx - NT_BRANCH;
        if (tid < 64) rowIdx[tid] = t * 64 + tid;
        W1T = soW1T; W2T = soW2T; W3T = soW3T16;
        bias1 = sob1; bias2 = sob2; bias3 = sob3;
    } else {
        const int c = tile_cmd[bx];
        if (c < 0) return;               // block-uniform
        if (tid < 64) rowIdx[tid] = perm[bx * 64 + tid];
        W1T = bW1T + (size_t)c * 256 * 640;
        W2T = bW2T + (size_t)c * 256 * 256;
        W3T = bW3T16 + (size_t)c * 16 * 256;
        bias1 = bb1 + c * 256; bias2 = bb2 + c * 256; bias3 = bb3 + c * 3;
    }
    __syncthreads();
    const int w = tid >> 6, lane = tid & 63, lq = lane >> 4, l16 = lane & 15;
    const int nb = w * 64;
    const f16* arow[4];
    #pragma unroll
    for (int mt = 0; mt < 4; ++mt) {
        const int g = rowIdx[mt * 16 + l16];
        arow[mt] = embF16 + (size_t)(g < 0 ? 0 : g) * 640;
    }
    const f16* brow[4];
    #pragma unroll
    for (int nt = 0; nt < 4; ++nt)
        brow[nt] = W1T + (size_t)(nb + nt * 16 + l16) * 640;

    f32x4 acc[4][4];
    #pragma unroll
    for (int mt = 0; mt < 4; ++mt)
        #pragma unroll
        for (int nt = 0; nt < 4; ++nt)
            acc[mt][nt] = (f32x4){0.f, 0.f, 0.f, 0.f};

    // ---- GEMM1: K=640, A+B frags straight from global, double-buffered, no barriers
    f16x8 a0[4], b0[4], a1[4], b1[4];
    {
        const int k = lq * 8;
        #pragma unroll
        for (int mt = 0; mt < 4; ++mt) a0[mt] = *(const f16x8*)(arow[mt] + k);
        #pragma unroll
        for (int nt = 0; nt < 4; ++nt) b0[nt] = *(const f16x8*)(brow[nt] + k);
    }
    for (int kp = 0; kp < 10; ++kp) {
        {
            const int k = kp * 64 + 32 + lq * 8;
            #pragma unroll
            for (int mt = 0; mt < 4; ++mt) a1[mt] = *(const f16x8*)(arow[mt] + k);
            #pragma unroll
            for (int nt = 0; nt < 4; ++nt) b1[nt] = *(const f16x8*)(brow[nt] + k);
        }
        #pragma unroll
        for (int mt = 0; mt < 4; ++mt)
            #pragma unroll
            for (int nt = 0; nt < 4; ++nt)
                acc[mt][nt] = __builtin_amdgcn_mfma_f32_16x16x32_f16(a0[mt], b0[nt], acc[mt][nt], 0, 0, 0);
        if (kp < 9) {
            const int k = (kp + 1) * 64 + lq * 8;
            #pragma unroll
            for (int mt = 0; mt < 4; ++mt) a0[mt] = *(const f16x8*)(arow[mt] + k);
            #pragma unroll
            for (int nt = 0; nt < 4; ++nt) b0[nt] = *(const f16x8*)(brow[nt] + k);
        }
        #pragma unroll
        for (int mt = 0; mt < 4; ++mt)
            #pragma unroll
            for (int nt = 0; nt < 4; ++nt)
                acc[mt][nt] = __builtin_amdgcn_mfma_f32_16x16x32_f16(a1[mt], b1[nt], acc[mt][nt], 0, 0, 0);
    }
    // h1 = relu(acc + b1) -> lds
    float b1r[4];
    #pragma unroll
    for (int nt = 0; nt < 4; ++nt) b1r[nt] = bias1[nb + nt * 16 + l16];
    #pragma unroll
    for (int mt = 0; mt < 4; ++mt)
        #pragma unroll
        for (int nt = 0; nt < 4; ++nt) {
            const int n = nb + nt * 16 + l16;
            #pragma unroll
            for (int r2 = 0; r2 < 4; ++r2) {
                const int m = mt * 16 + lq * 4 + r2;
                const float v = acc[mt][nt][r2] + b1r[nt];
                lds[m * 264 + n] = (f16)(v > 0.f ? v : 0.f);
            }
            acc[mt][nt] = (f32x4){0.f, 0.f, 0.f, 0.f};
        }
    __syncthreads();
    // ---- GEMM2: K=256, A=h1 (LDS), B pipelined from global
    const f16* brow2[4];
    #pragma unroll
    for (int nt = 0; nt < 4; ++nt)
        brow2[nt] = W2T + (size_t)(nb + nt * 16 + l16) * 256;
    f16x8 c0[4], c1[4];
    {
        const int k = lq * 8;
        #pragma unroll
        for (int nt = 0; nt < 4; ++nt) c0[nt] = *(const f16x8*)(brow2[nt] + k);
    }
    for (int kp = 0; kp < 4; ++kp) {
        {
            const int k = kp * 64 + 32 + lq * 8;
            #pragma unroll
            for (int nt = 0; nt < 4; ++nt) c1[nt] = *(const f16x8*)(brow2[nt] + k);
        }
        {
            const int koff = kp * 64 + lq * 8;
            f16x8 af[4];
            #pragma unroll
            for (int mt = 0; mt < 4; ++mt)
                af[mt] = *(const f16x8*)(&lds[(mt * 16 + l16) * 264 + koff]);
            #pragma unroll
            for (int mt = 0; mt < 4; ++mt)
                #pragma unroll
                for (int nt = 0; nt < 4; ++nt)
                    acc[mt][nt] = __builtin_amdgcn_mfma_f32_16x16x32_f16(af[mt], c0[nt], acc[mt][nt], 0, 0, 0);
        }
        if (kp < 3) {
            const int k = (kp + 1) * 64 + lq * 8;
            #pragma unroll
            for (int nt = 0; nt < 4; ++nt) c0[nt] = *(const f16x8*)(brow2[nt] + k);
        }
        {
            const int koff = kp * 64 + 32 + lq * 8;
            f16x8 af[4];
            #pragma unroll
            for (int mt = 0; mt < 4; ++mt)
                af[mt] = *(const f16x8*)(&lds[(mt * 16 + l16) * 264 + koff]);
            #pragma unroll
            for (int mt = 0; mt < 4; ++mt)
                #pragma unroll
                for (int nt = 0; nt < 4; ++nt)
                    acc[mt][nt] = __builtin_amdgcn_mfma_f32_16x16x32_f16(af[mt], c1[nt], acc[mt][nt], 0, 0, 0);
        }
    }
    // h2 = relu(acc + b2) -> lds (barrier both sides: others may still read h1)
    float b2r[4];
    #pragma unroll
    for (int nt = 0; nt < 4; ++nt) b2r[nt] = bias2[nb + nt * 16 + l16];
    __syncthreads();
    #pragma unroll
    for (int mt = 0; mt < 4; ++mt)
        #pragma unroll
        for (int nt = 0; nt < 4; ++nt) {
            const int n = nb + nt * 16 + l16;
            #pragma unroll
            for (int r2 = 0; r2 < 4; ++r2) {
                const int m = mt * 16 + lq * 4 + r2;
                const float v = acc[mt][nt][r2] + b2r[nt];
                lds[m * 264 + n] = (f16)(v > 0.f ? v : 0.f);
            }
        }
    __syncthreads();
    // ---- GEMM3: [64,256]@[256,16] via MFMA; wave w owns rows w*16..w*16+15
    f32x4 acc3 = (f32x4){0.f, 0.f, 0.f, 0.f};
    const f16* w3row = W3T + (size_t)l16 * 256;
    #pragma unroll
    for (int ks = 0; ks < 8; ++ks) {
        const int koff = ks * 32 + lq * 8;
        const f16x8 af = *(const f16x8*)(&lds[(w * 16 + l16) * 264 + koff]);
        const f16x8 bf = *(const f16x8*)(w3row + koff);
        acc3 = __builtin_amdgcn_mfma_f32_16x16x32_f16(af, bf, acc3, 0, 0, 0);
    }
    const int orow = w * 16 + lq * 4;
    if (!is_speed) {
        if (l16 < 3) {
            const float b3 = bias3[l16];
            #pragma unroll
            for (int r2 = 0; r2 < 4; ++r2) {
                const int g = rowIdx[orow + r2];
                if (g >= 0)
                    out[(size_t)g * 3 + l16] = 1.f / (1.f + __expf(-(acc3[r2] + b3)));
            }
        }
    } else {
        if (l16 == 0) {
            const float b3 = bias3[0];
            #pragma unroll
            for (int r2 = 0; r2 < 4; ++r2)
                out[(size_t)3 * B_ROWS + rowIdx[orow + r2]] = acc3[r2] + b3;
        }
    }
}

extern "C" void kernel_launch(void* const* d_in, const int* in_sizes, int n_in,
                              void* d_out, int out_size, void* d_ws, size_t ws_size,
                              hipStream_t stream) {
    (void)in_sizes; (void)n_in; (void)out_size; (void)ws_size;
    const float* embedding = (const float*)d_in[0];
    const float* speed     = (const float*)d_in[1];
    const int*   command   = (const int*)d_in[2];
    const float* si_W1 = (const float*)d_in[3];
    const float* si_b1 = (const float*)d_in[4];
    const float* si_W2 = (const float*)d_in[5];
    const float* si_b2 = (const float*)d_in[6];
    const float* bW1   = (const float*)d_in[7];
    const float* bb1   = (const float*)d_in[8];
    const float* bW2   = (const float*)d_in[9];
    const float* bb2   = (const float*)d_in[10];
    const float* bW3   = (const float*)d_in[11];
    const float* bb3   = (const float*)d_in[12];
    const float* so_W1 = (const float*)d_in[13];
    const float* so_b1 = (const float*)d_in[14];
    const float* so_W2 = (const float*)d_in[15];
    const float* so_b2 = (const float*)d_in[16];
    const float* so_W3 = (const float*)d_in[17];
    const float* so_b3 = (const float*)d_in[18];
    float* out = (float*)d_out;

    char* ws = (char*)d_ws;
    f16* embF16 = (f16*)(ws + OFF_EMBF16);
    f16* siW2T  = (f16*)(ws + OFF_SIW2T);
    f16* bW1T   = (f16*)(ws + OFF_BW1T);
    f16* bW2T   = (f16*)(ws + OFF_BW2T);
    f16* soW1T  = (f16*)(ws + OFF_SOW1T);
    f16* soW2T  = (f16*)(ws + OFF_SOW2T);
    f16* bW3T16 = (f16*)(ws + OFF_BW3T16);
    f16* soW3T16= (f16*)(ws + OFF_SOW3T16);
    int* counts = (int*)(ws + OFF_COUNTS);
    int* cursors= (int*)(ws + OFF_CURSORS);
    int* binBase= (int*)(ws + OFF_BINBASE);
    int* tile_cmd = (int*)(ws + OFF_TILECMD);
    int* perm   = (int*)(ws + OFF_PERM);

    prep_kernel<<<1859, dim3(32, 8), 0, stream>>>(
        si_W2, bW1, bW2, so_W1, so_W2, bW3, so_W3,
        siW2T, bW1T, bW2T, soW1T, soW2T, bW3T16, soW3T16,
        counts, cursors, perm);
    pack_kernel<<<1024, 256, 0, stream>>>(
        embedding, speed, si_W1, si_b1, siW2T, si_b2, command, embF16, counts);
    plan_kernel<<<1, 256, 0, stream>>>(counts, binBase, tile_cmd);
    place_kernel<<<256, 256, 0, stream>>>(command, binBase, cursors, perm);
    heads_kernel<<<NT_BRANCH + NT_SPEED, 256, 0, stream>>>(
        embF16, perm, tile_cmd,
        bW1T, bW2T, bW3T16, bb1, bb2, bb3,
        soW1T, soW2T, soW3T16, so_b1, so_b2, so_b3, out);
}

// Round 3
// 376.021 us; speedup vs baseline: 1.2646x; 1.2646x over previous
//
#include <hip/hip_runtime.h>
#include <cstdint>
#include <cstddef>

typedef _Float16 f16;
typedef f16 f16x8 __attribute__((ext_vector_type(8)));
typedef float f32x4 __attribute__((ext_vector_type(4)));

#define B_ROWS 65536
#define NT_BRANCH 1030   // worst-case branch tiles: 1024 + 6 bins' padding
#define NT_SPEED 1024    // 65536/64

// ---------------- ws layout (all offsets 256B-aligned) ----------------
constexpr size_t OFF_SF16   = 0;
constexpr size_t SZ_SF16    = (size_t)B_ROWS * 128 * 2;        // 16,777,216
constexpr size_t OFF_SIW2T  = OFF_SF16 + SZ_SF16;
constexpr size_t SZ_SIW2T   = (size_t)128 * 256 * 2;
constexpr size_t OFF_BW1T   = OFF_SIW2T + SZ_SIW2T;
constexpr size_t SZ_BW1T    = (size_t)6 * 256 * 640 * 2;
constexpr size_t OFF_BW2T   = OFF_BW1T + SZ_BW1T;
constexpr size_t SZ_BW2T    = (size_t)6 * 256 * 256 * 2;
constexpr size_t OFF_SOW1T  = OFF_BW2T + SZ_BW2T;
constexpr size_t SZ_SOW1T   = (size_t)256 * 640 * 2;
constexpr size_t OFF_SOW2T  = OFF_SOW1T + SZ_SOW1T;
constexpr size_t SZ_SOW2T   = (size_t)256 * 256 * 2;
constexpr size_t OFF_BW3T16 = OFF_SOW2T + SZ_SOW2T;
constexpr size_t SZ_BW3T16  = (size_t)6 * 16 * 256 * 2;        // zero-padded cols 3..15
constexpr size_t OFF_SOW3T16= OFF_BW3T16 + SZ_BW3T16;
constexpr size_t SZ_SOW3T16 = (size_t)16 * 256 * 2;
constexpr size_t OFF_COUNTS = OFF_SOW3T16 + SZ_SOW3T16;
constexpr size_t OFF_CURSORS= OFF_COUNTS + 256;
constexpr size_t OFF_BINBASE= OFF_CURSORS + 256;
constexpr size_t OFF_TILECMD= OFF_BINBASE + 256;
constexpr size_t OFF_PERM   = OFF_TILECMD + 4352;
constexpr size_t WS_NEEDED  = OFF_PERM + (size_t)NT_BRANCH * 64 * 4;  // ~20.5 MB

// ---------------- prep: transpose-cast weights + W3T16 + init sort scratch ----------------
__global__ void prep_kernel(const float* __restrict__ siW2,
                            const float* __restrict__ bW1,
                            const float* __restrict__ bW2,
                            const float* __restrict__ soW1,
                            const float* __restrict__ soW2,
                            const float* __restrict__ bW3,
                            const float* __restrict__ soW3,
                            f16* __restrict__ siW2T, f16* __restrict__ bW1T,
                            f16* __restrict__ bW2T, f16* __restrict__ soW1T,
                            f16* __restrict__ soW2T,
                            f16* __restrict__ bW3T16, f16* __restrict__ soW3T16,
                            int* __restrict__ counts, int* __restrict__ cursors,
                            int* __restrict__ perm)
{
    const int bx = blockIdx.x;
    const int tx = threadIdx.x, ty = threadIdx.y;
    const int tid = ty * 32 + tx;
    if (bx >= 1601) {                       // perm init + counter zero
        const int ib = bx - 1601;
        const int idx = ib * 256 + tid;
        if (idx < NT_BRANCH * 64) perm[idx] = -1;
        if (ib == 0 && tid < 6) { counts[tid] = 0; cursors[tid] = 0; }
        return;
    }
    if (bx == 1600) {                       // W3 -> padded-16-col f16, [n][k] layout
        for (int i = tid; i < 6 * 16 * 256; i += 256) {
            const int c = i >> 12, rem = i & 4095, n = rem >> 8, k = rem & 255;
            bW3T16[i] = (n < 3) ? (f16)bW3[((size_t)c * 256 + k) * 3 + n] : (f16)0;
        }
        for (int i = tid; i < 16 * 256; i += 256) {
            const int n = i >> 8, k = i & 255;
            soW3T16[i] = (n == 0) ? (f16)soW3[k] : (f16)0;
        }
        return;
    }
    const float* in; f16* out; int R, C, lb;
    if (bx < 960)       { int m = bx / 160;        lb = bx - m * 160;       in = bW1 + (size_t)m * 640 * 256; out = bW1T + (size_t)m * 640 * 256; R = 640; C = 256; }
    else if (bx < 1344) { int m = (bx - 960) / 64; lb = (bx - 960) - m * 64; in = bW2 + (size_t)m * 256 * 256; out = bW2T + (size_t)m * 256 * 256; R = 256; C = 256; }
    else if (bx < 1504) { lb = bx - 1344; in = soW1; out = soW1T; R = 640; C = 256; }
    else if (bx < 1568) { lb = bx - 1504; in = soW2; out = soW2T; R = 256; C = 256; }
    else                { lb = bx - 1568; in = siW2; out = siW2T; R = 256; C = 128; }
    const int txt = C >> 5;
    const int c0 = (lb % txt) << 5;
    const int r0 = (lb / txt) << 5;
    __shared__ float tile[32][33];
    #pragma unroll
    for (int i = 0; i < 4; ++i)
        tile[tx][ty + 8 * i] = in[(size_t)(r0 + ty + 8 * i) * C + c0 + tx];
    __syncthreads();
    #pragma unroll
    for (int i = 0; i < 4; ++i)
        out[(size_t)(c0 + ty + 8 * i) * R + r0 + tx] = (f16)tile[ty + 8 * i][tx];
}

// ---------------- speed_in MLP (+ fused histogram): sF16 = relu(speed*W1+b1)@W2+b2 ----------------
__global__ __launch_bounds__(256) void speedin_kernel(
    const float* __restrict__ speed,
    const float* __restrict__ siW1, const float* __restrict__ sib1,
    const f16* __restrict__ siW2T, const float* __restrict__ sib2,
    const int* __restrict__ cmd,
    f16* __restrict__ sF16, int* __restrict__ counts)
{
    __shared__ f16 H[64 * 264];
    __shared__ float spd[64];
    __shared__ int h[6];
    const int tid = threadIdx.x;
    const int rb = blockIdx.x * 64;
    if (tid < 6) h[tid] = 0;
    __syncthreads();
    if (tid < 64) {
        spd[tid] = speed[rb + tid];
        atomicAdd(&h[cmd[rb + tid] - 1], 1);
    }
    __syncthreads();
    if (tid < 6 && h[tid] > 0) atomicAdd(&counts[tid], h[tid]);
    {
        const float w1 = siW1[tid], b1v = sib1[tid];
        #pragma unroll 4
        for (int r = 0; r < 64; ++r) {
            float hv = spd[r] * w1 + b1v;
            H[r * 264 + tid] = (f16)(hv > 0.f ? hv : 0.f);
        }
    }
    __syncthreads();
    const int w = tid >> 6, lane = tid & 63, lq = lane >> 4, l16 = lane & 15;
    const int nb = w * 32;
    f32x4 acc[4][2];
    #pragma unroll
    for (int mt = 0; mt < 4; ++mt)
        #pragma unroll
        for (int nt = 0; nt < 2; ++nt)
            acc[mt][nt] = (f32x4){0.f, 0.f, 0.f, 0.f};
    for (int ks = 0; ks < 8; ++ks) {
        const int koff = ks * 32 + lq * 8;
        f16x8 af[4], bf[2];
        #pragma unroll
        for (int mt = 0; mt < 4; ++mt)
            af[mt] = *(const f16x8*)(&H[(mt * 16 + l16) * 264 + koff]);
        #pragma unroll
        for (int nt = 0; nt < 2; ++nt)
            bf[nt] = *(const f16x8*)(siW2T + (size_t)(nb + nt * 16 + l16) * 256 + koff);
        #pragma unroll
        for (int mt = 0; mt < 4; ++mt)
            #pragma unroll
            for (int nt = 0; nt < 2; ++nt)
                acc[mt][nt] = __builtin_amdgcn_mfma_f32_16x16x32_f16(af[mt], bf[nt], acc[mt][nt], 0, 0, 0);
    }
    #pragma unroll
    for (int mt = 0; mt < 4; ++mt)
        #pragma unroll
        for (int nt = 0; nt < 2; ++nt) {
            const int n = nb + nt * 16 + l16;
            const float bv = sib2[n];
            #pragma unroll
            for (int r2 = 0; r2 < 4; ++r2) {
                const int m = mt * 16 + lq * 4 + r2;
                sF16[(size_t)(rb + m) * 128 + n] = (f16)(acc[mt][nt][r2] + bv);
            }
        }
}

// ---------------- plan: bin bases + tile->command map ----------------
__global__ void plan_kernel(const int* __restrict__ counts,
                            int* __restrict__ binBase, int* __restrict__ tile_cmd) {
    __shared__ int tbase[7];
    if (threadIdx.x == 0) {
        int base = 0, tb = 0;
        for (int c = 0; c < 6; ++c) {
            binBase[c] = base;
            tbase[c] = tb;
            const int nt = (counts[c] + 63) >> 6;
            tb += nt;
            base += nt << 6;
        }
        tbase[6] = tb;
    }
    __syncthreads();
    for (int t = threadIdx.x; t < NT_BRANCH; t += 256) {
        int c = -1;
        #pragma unroll
        for (int j = 0; j < 6; ++j)
            if (t >= tbase[j] && t < tbase[j + 1]) c = j;
        tile_cmd[t] = c;
    }
}

__global__ void place_kernel(const int* __restrict__ cmd,
                             const int* __restrict__ binBase,
                             int* __restrict__ cursors, int* __restrict__ perm) {
    __shared__ int lcnt[6], lbase[6];
    const int tid = threadIdx.x;
    if (tid < 6) lcnt[tid] = 0;
    __syncthreads();
    const int i = blockIdx.x * 256 + tid;
    const int c = cmd[i] - 1;
    const int myr = atomicAdd(&lcnt[c], 1);
    __syncthreads();
    if (tid < 6) lbase[tid] = atomicAdd(&cursors[tid], lcnt[tid]);
    __syncthreads();
    perm[binBase[c] + lbase[c] + myr] = i;
}

// Per-thread staging load: one f16x8 (8 cols) of row `grow`, chunk kc (64 cols).
// kc<8: fp32 embedding cols kc*64..; kc>=8: f16 sF16 cols (kc-8)*64..
__device__ __forceinline__ f16x8 stage_load(const float* __restrict__ srcF,
                                            const f16* __restrict__ srcH,
                                            int kc, int p) {
    if (kc < 8) {
        const float* s = srcF + kc * 64 + p * 8;
        const float4 f0 = ((const float4*)s)[0];
        const float4 f1 = ((const float4*)s)[1];
        f16x8 v;
        v[0] = (f16)f0.x; v[1] = (f16)f0.y; v[2] = (f16)f0.z; v[3] = (f16)f0.w;
        v[4] = (f16)f1.x; v[5] = (f16)f1.y; v[6] = (f16)f1.z; v[7] = (f16)f1.w;
        return v;
    } else {
        return *(const f16x8*)(srcH + (kc - 8) * 64 + p * 8);
    }
}

// ---------------- heads: fused 3-layer MLP, LDS-staged A, deep pipeline ----------------
// 512 threads = 8 waves; wave-tile 64x32 (acc 4x2); M=64 rows per block.
// LDS: A double buffer 2x[64][72] aliased with h buffer [64][264] (33792 f16).
__global__ __launch_bounds__(512, 4) void heads_kernel(
    const float* __restrict__ emb,        // [B,512] fp32
    const f16* __restrict__ sF16,         // [B,128]
    const int* __restrict__ perm, const int* __restrict__ tile_cmd,
    const f16* __restrict__ bW1T, const f16* __restrict__ bW2T,
    const f16* __restrict__ bW3T16,
    const float* __restrict__ bb1, const float* __restrict__ bb2,
    const float* __restrict__ bb3,
    const f16* __restrict__ soW1T, const f16* __restrict__ soW2T,
    const f16* __restrict__ soW3T16,
    const float* __restrict__ sob1, const float* __restrict__ sob2,
    const float* __restrict__ sob3,
    float* __restrict__ out)
{
    __shared__ f16 smem[16896];           // A dbuf (2*4608) aliases h buffer (64*264)
    __shared__ int rowIdx[64];
    const int bx = blockIdx.x;
    const int tid = threadIdx.x;
    const bool is_speed = (bx >= NT_BRANCH);
    const f16 *W1T, *W2T, *W3T;
    const float *bias1, *bias2, *bias3;
    if (is_speed) {
        const int t = bx - NT_BRANCH;
        if (tid < 64) rowIdx[tid] = t * 64 + tid;
        W1T = soW1T; W2T = soW2T; W3T = soW3T16;
        bias1 = sob1; bias2 = sob2; bias3 = sob3;
    } else {
        const int c = tile_cmd[bx];
        if (c < 0) return;               // block-uniform
        if (tid < 64) rowIdx[tid] = perm[bx * 64 + tid];
        W1T = bW1T + (size_t)c * 256 * 640;
        W2T = bW2T + (size_t)c * 256 * 256;
        W3T = bW3T16 + (size_t)c * 16 * 256;
        bias1 = bb1 + c * 256; bias2 = bb2 + c * 256; bias3 = bb3 + c * 3;
    }
    __syncthreads();

    // staging role: thread covers row r, 8-col group p of each 64-col chunk
    const int r = tid >> 3, p = tid & 7;
    int growS = rowIdx[r]; if (growS < 0) growS = 0;
    const float* srcF = emb + (size_t)growS * 512;
    const f16*   srcH = sF16 + (size_t)growS * 128;
    const int pOff = r * 72 + p * 8;

    const int w = tid >> 6, lane = tid & 63, lq = lane >> 4, l16 = lane & 15;
    const int nb = w * 32;               // wave's N slice of 256
    const f16* brow[2];
    #pragma unroll
    for (int nt = 0; nt < 2; ++nt)
        brow[nt] = W1T + (size_t)(nb + nt * 16 + l16) * 640;

    f32x4 acc[4][2];
    #pragma unroll
    for (int mt = 0; mt < 4; ++mt)
        #pragma unroll
        for (int nt = 0; nt < 2; ++nt)
            acc[mt][nt] = (f32x4){0.f, 0.f, 0.f, 0.f};

    // ---- GEMM1: K=640 in 10 chunks of 64; A staged to LDS 3 iters ahead; B 2 ahead
    f16x8 sreg[4];
    f16x8 Bb[2][2][2];                    // [parity][ks][nt]
    #pragma unroll
    for (int j = 0; j < 4; ++j)
        sreg[j] = stage_load(srcF, srcH, j, p);
    #pragma unroll
    for (int ks = 0; ks < 2; ++ks)
        #pragma unroll
        for (int nt = 0; nt < 2; ++nt) {
            Bb[0][ks][nt] = *(const f16x8*)(brow[nt] + 0 * 64 + ks * 32 + lq * 8);
            Bb[1][ks][nt] = *(const f16x8*)(brow[nt] + 1 * 64 + ks * 32 + lq * 8);
        }
    *(f16x8*)(smem + pOff) = sreg[0];     // buf0 <- chunk0
    __syncthreads();
    #pragma unroll
    for (int kc = 0; kc < 10; ++kc) {
        f16* cur = smem + (kc & 1) * 4608;
        if (kc < 9)                        // publish chunk kc+1 into other buffer
            *(f16x8*)(smem + ((kc + 1) & 1) * 4608 + pOff) = sreg[(kc + 1) & 3];
        if (kc < 6)                        // refill freed slot with chunk kc+4
            sreg[kc & 3] = stage_load(srcF, srcH, kc + 4, p);
        #pragma unroll
        for (int ks = 0; ks < 2; ++ks) {
            f16x8 a[4];
            #pragma unroll
            for (int mt = 0; mt < 4; ++mt)
                a[mt] = *(const f16x8*)(cur + (mt * 16 + l16) * 72 + ks * 32 + lq * 8);
            #pragma unroll
            for (int mt = 0; mt < 4; ++mt)
                #pragma unroll
                for (int nt = 0; nt < 2; ++nt)
                    acc[mt][nt] = __builtin_amdgcn_mfma_f32_16x16x32_f16(a[mt], Bb[kc & 1][ks][nt], acc[mt][nt], 0, 0, 0);
        }
        if (kc < 8) {                      // refill B parity slot with chunk kc+2
            #pragma unroll
            for (int ks = 0; ks < 2; ++ks)
                #pragma unroll
                for (int nt = 0; nt < 2; ++nt)
                    Bb[kc & 1][ks][nt] = *(const f16x8*)(brow[nt] + (kc + 2) * 64 + ks * 32 + lq * 8);
        }
        __syncthreads();
    }

    // prefetch GEMM2 B (ks=0) behind the epilogue
    const f16* brow2[2];
    #pragma unroll
    for (int nt = 0; nt < 2; ++nt)
        brow2[nt] = W2T + (size_t)(nb + nt * 16 + l16) * 256;
    f16x8 Bd[2][2];
    #pragma unroll
    for (int nt = 0; nt < 2; ++nt)
        Bd[0][nt] = *(const f16x8*)(brow2[nt] + lq * 8);

    // h1 = relu(acc + b1) -> smem [64][264]
    #pragma unroll
    for (int mt = 0; mt < 4; ++mt)
        #pragma unroll
        for (int nt = 0; nt < 2; ++nt) {
            const int n = nb + nt * 16 + l16;
            const float bv = bias1[n];
            #pragma unroll
            for (int r2 = 0; r2 < 4; ++r2) {
                const int m = mt * 16 + lq * 4 + r2;
                const float v = acc[mt][nt][r2] + bv;
                smem[m * 264 + n] = (f16)(v > 0.f ? v : 0.f);
            }
            acc[mt][nt] = (f32x4){0.f, 0.f, 0.f, 0.f};
        }
    __syncthreads();

    // ---- GEMM2: K=256, A=h1 (LDS), B dbuf one ks ahead
    #pragma unroll
    for (int ks = 0; ks < 8; ++ks) {
        if (ks < 7) {
            #pragma unroll
            for (int nt = 0; nt < 2; ++nt)
                Bd[(ks + 1) & 1][nt] = *(const f16x8*)(brow2[nt] + (ks + 1) * 32 + lq * 8);
        }
        f16x8 a[4];
        #pragma unroll
        for (int mt = 0; mt < 4; ++mt)
            a[mt] = *(const f16x8*)(&smem[(mt * 16 + l16) * 264 + ks * 32 + lq * 8]);
        #pragma unroll
        for (int mt = 0; mt < 4; ++mt)
            #pragma unroll
            for (int nt = 0; nt < 2; ++nt)
                acc[mt][nt] = __builtin_amdgcn_mfma_f32_16x16x32_f16(a[mt], Bd[ks & 1][nt], acc[mt][nt], 0, 0, 0);
    }
    __syncthreads();
    // h2 = relu(acc + b2) -> smem
    #pragma unroll
    for (int mt = 0; mt < 4; ++mt)
        #pragma unroll
        for (int nt = 0; nt < 2; ++nt) {
            const int n = nb + nt * 16 + l16;
            const float bv = bias2[n];
            #pragma unroll
            for (int r2 = 0; r2 < 4; ++r2) {
                const int m = mt * 16 + lq * 4 + r2;
                const float v = acc[mt][nt][r2] + bv;
                smem[m * 264 + n] = (f16)(v > 0.f ? v : 0.f);
            }
        }
    __syncthreads();
    // ---- GEMM3: [64,256]@[256,16] via MFMA; waves 0-3 own 16-row slices
    if (w < 4) {
        f32x4 acc3 = (f32x4){0.f, 0.f, 0.f, 0.f};
        const f16* w3row = W3T + (size_t)l16 * 256;
        #pragma unroll
        for (int ks = 0; ks < 8; ++ks) {
            const int koff = ks * 32 + lq * 8;
            const f16x8 af = *(const f16x8*)(&smem[(w * 16 + l16) * 264 + koff]);
            const f16x8 bf = *(const f16x8*)(w3row + koff);
            acc3 = __builtin_amdgcn_mfma_f32_16x16x32_f16(af, bf, acc3, 0, 0, 0);
        }
        const int orow = w * 16 + lq * 4;
        if (!is_speed) {
            if (l16 < 3) {
                const float b3 = bias3[l16];
                #pragma unroll
                for (int r2 = 0; r2 < 4; ++r2) {
                    const int g = rowIdx[orow + r2];
                    if (g >= 0)
                        out[(size_t)g * 3 + l16] = 1.f / (1.f + __expf(-(acc3[r2] + b3)));
                }
            }
        } else {
            if (l16 == 0) {
                const float b3 = bias3[0];
                #pragma unroll
                for (int r2 = 0; r2 < 4; ++r2)
                    out[(size_t)3 * B_ROWS + rowIdx[orow + r2]] = acc3[r2] + b3;
            }
        }
    }
}

extern "C" void kernel_launch(void* const* d_in, const int* in_sizes, int n_in,
                              void* d_out, int out_size, void* d_ws, size_t ws_size,
                              hipStream_t stream) {
    (void)in_sizes; (void)n_in; (void)out_size; (void)ws_size;
    const float* embedding = (const float*)d_in[0];
    const float* speed     = (const float*)d_in[1];
    const int*   command   = (const int*)d_in[2];
    const float* si_W1 = (const float*)d_in[3];
    const float* si_b1 = (const float*)d_in[4];
    const float* si_W2 = (const float*)d_in[5];
    const float* si_b2 = (const float*)d_in[6];
    const float* bW1   = (const float*)d_in[7];
    const float* bb1   = (const float*)d_in[8];
    const float* bW2   = (const float*)d_in[9];
    const float* bb2   = (const float*)d_in[10];
    const float* bW3   = (const float*)d_in[11];
    const float* bb3   = (const float*)d_in[12];
    const float* so_W1 = (const float*)d_in[13];
    const float* so_b1 = (const float*)d_in[14];
    const float* so_W2 = (const float*)d_in[15];
    const float* so_b2 = (const float*)d_in[16];
    const float* so_W3 = (const float*)d_in[17];
    const float* so_b3 = (const float*)d_in[18];
    float* out = (float*)d_out;

    char* ws = (char*)d_ws;
    f16* sF16   = (f16*)(ws + OFF_SF16);
    f16* siW2T  = (f16*)(ws + OFF_SIW2T);
    f16* bW1T   = (f16*)(ws + OFF_BW1T);
    f16* bW2T   = (f16*)(ws + OFF_BW2T);
    f16* soW1T  = (f16*)(ws + OFF_SOW1T);
    f16* soW2T  = (f16*)(ws + OFF_SOW2T);
    f16* bW3T16 = (f16*)(ws + OFF_BW3T16);
    f16* soW3T16= (f16*)(ws + OFF_SOW3T16);
    int* counts = (int*)(ws + OFF_COUNTS);
    int* cursors= (int*)(ws + OFF_CURSORS);
    int* binBase= (int*)(ws + OFF_BINBASE);
    int* tile_cmd = (int*)(ws + OFF_TILECMD);
    int* perm   = (int*)(ws + OFF_PERM);

    prep_kernel<<<1859, dim3(32, 8), 0, stream>>>(
        si_W2, bW1, bW2, so_W1, so_W2, bW3, so_W3,
        siW2T, bW1T, bW2T, soW1T, soW2T, bW3T16, soW3T16,
        counts, cursors, perm);
    speedin_kernel<<<1024, 256, 0, stream>>>(
        speed, si_W1, si_b1, siW2T, si_b2, command, sF16, counts);
    plan_kernel<<<1, 256, 0, stream>>>(counts, binBase, tile_cmd);
    place_kernel<<<256, 256, 0, stream>>>(command, binBase, cursors, perm);
    heads_kernel<<<NT_BRANCH + NT_SPEED, 512, 0, stream>>>(
        embedding, sF16, perm, tile_cmd,
        bW1T, bW2T, bW3T16, bb1, bb2, bb3,
        soW1T, soW2T, soW3T16, so_b1, so_b2, so_b3, out);
}